// Round 3
// baseline (601.924 us; speedup 1.0000x reference)
//
#include <hip/hip_runtime.h>
#include <hip/hip_bf16.h>
#include <math.h>

// Workspace layout (bytes) — total 984,064 B (~0.94 MiB), deliberately < 1 MiB:
//   xb : [4][1024][112] __hip_bfloat16  @ 0        (917,504 B)  conv1d input
//   fo : [4][1024]      float           @ 917504   ( 16,384 B)  feat_o (fp32-exact)
//   sw : [4][64][49]    float           @ 933888   ( 50,176 B)  post-sigmoid slice weights
#define XB_OFF 0
#define FO_OFF 917504
#define SW_OFF 933888

// ---------------------------------------------------------------------------
// K1: fused pool + feat_o.  One block per (b, c): waves read the 112 slices
// (1 KB coalesced each), shfl-reduce sum/max, park in LDS; then write bf16
// x rows for the conv AND compute feat_o from the fp32 LDS values (so the
// head's direct input never sees bf16 rounding).
__global__ __launch_bounds__(256) void k_pool(const float* __restrict__ oct,
                                              __hip_bfloat16* __restrict__ xb,
                                              float* __restrict__ fo) {
    __shared__ float sm[112];
    __shared__ float mxm[112];
    int bc = blockIdx.x;                    // b*512 + c
    int b = bc >> 9, c = bc & 511;
    int w = threadIdx.x >> 6, lane = threadIdx.x & 63;
    for (int mm = 0; mm < 28; mm++) {
        int m = mm * 4 + w;
        const float4* p = (const float4*)(oct + ((size_t)(b * 112 + m) * 512 + c) * 256);
        float4 v = p[lane];
        float s  = v.x + v.y + v.z + v.w;
        float mx = fmaxf(fmaxf(v.x, v.y), fmaxf(v.z, v.w));
#pragma unroll
        for (int off = 32; off >= 1; off >>= 1) {
            s  += __shfl_xor(s, off);
            mx  = fmaxf(mx, __shfl_xor(mx, off));
        }
        if (lane == 0) { sm[m] = s; mxm[m] = mx; }
    }
    __syncthreads();
    if (threadIdx.x < 112) {
        int m = threadIdx.x;
        xb[((size_t)b * 1024 + c) * 112 + m]       = __float2bfloat16(sm[m] * (1.0f / 256.0f));
        xb[((size_t)b * 1024 + 512 + c) * 112 + m] = __float2bfloat16(mxm[m]);
    }
    if (w == 0) {
        // feat_o_avg = max_m fv (== fv at argmax fv, exactly);
        // feat_o_max = fv at argmax_m fv_max (first-occurrence ties like np).
        float v0 = sm[lane];
        float v1 = (lane + 64 < 112) ? sm[lane + 64] : -INFINITY;
        float mxf = fmaxf(v0, v1);
        float m0 = mxm[lane];
        float m1 = (lane + 64 < 112) ? mxm[lane + 64] : -INFINITY;
        float av; int ai;
        if (m1 > m0) { av = m1; ai = lane + 64; } else { av = m0; ai = lane; }
#pragma unroll
        for (int off = 32; off >= 1; off >>= 1) {
            float ov = __shfl_xor(av, off);
            int   oi = __shfl_xor(ai, off);
            if (ov > av || (ov == av && oi < ai)) { av = ov; ai = oi; }
            mxf = fmaxf(mxf, __shfl_xor(mxf, off));
        }
        if (lane == 0) {
            fo[b * 1024 + c]       = mxf * (1.0f / 256.0f);
            fo[b * 1024 + 512 + c] = sm[ai] * (1.0f / 256.0f);
        }
    }
}

// ---------------------------------------------------------------------------
// K2: conv1d (Cin=1024, K=64, L=112 -> 49) full-K per block (b, co).
// 4 chunks of 256 ci staged into LDS (rows padded to 61 uints: bank stride
// 61 = 29 mod 32, coprime -> conflict-free per-lane row reads). Waves 0,1
// cover l 0..24, waves 2,3 cover l 25..48; each wave-pair splits ci.
template <int NL>
__device__ __forceinline__ void conv_inner(const __hip_bfloat16* __restrict__ xrow,
                                           const float* __restrict__ wrow,
                                           float* __restrict__ acc) {
#pragma unroll
    for (int kc = 0; kc < 4; kc++) {
        float ww[16], xw[NL + 15];
#pragma unroll
        for (int j = 0; j < 16; j++) ww[j] = wrow[kc * 16 + j];
#pragma unroll
        for (int j = 0; j < NL + 15; j++) xw[j] = __bfloat162float(xrow[kc * 16 + j]);
#pragma unroll
        for (int k = 0; k < 16; k++)
#pragma unroll
            for (int i = 0; i < NL; i++)
                acc[i] += ww[k] * xw[k + i];
    }
}

__global__ __launch_bounds__(256) void k_conv(const __hip_bfloat16* __restrict__ xb,
                                              const float* __restrict__ w1,
                                              const float* __restrict__ b1,
                                              float* __restrict__ sw) {
    __shared__ unsigned int xs[256 * 61];   // 62,464 B: 256 bf16 rows of 112 (+pad)
    __shared__ float red[4][25];
    int bx = blockIdx.x;                    // b*64 + co
    int b = bx >> 6, co = bx & 63;
    int t = threadIdx.x, wv = t >> 6, lane = t & 63;
    int lh = wv >> 1, h = wv & 1;
    int l0 = lh * 25;
    float acc[25];
#pragma unroll
    for (int i = 0; i < 25; i++) acc[i] = 0.f;
    const unsigned int* gxb = (const unsigned int*)xb;
    for (int chunk = 0; chunk < 4; chunk++) {
        __syncthreads();                    // LDS reuse guard
        for (int idx = t; idx < 256 * 56; idx += 256) {
            int ci = idx / 56, j = idx % 56;
            xs[ci * 61 + j] = gxb[((size_t)b * 1024 + chunk * 256 + ci) * 56 + j];
        }
        __syncthreads();
        const __hip_bfloat16* xls = (const __hip_bfloat16*)xs;
        for (int g = 0; g < 2; g++) {
            int cil = h * 128 + g * 64 + lane;
            const __hip_bfloat16* xrow = xls + cil * 122 + l0;
            const float* wrow = w1 + ((size_t)co * 1024 + chunk * 256 + cil) * 64;
            if (lh == 0) conv_inner<25>(xrow, wrow, acc);
            else         conv_inner<24>(xrow, wrow, acc);
        }
    }
    // wave butterfly: every lane holds the 64-lane ci-sum
#pragma unroll
    for (int i = 0; i < 25; i++) {
#pragma unroll
        for (int off = 32; off >= 1; off >>= 1)
            acc[i] += __shfl_xor(acc[i], off);
    }
    if (lane < 25) red[wv][lane] = acc[lane];
    __syncthreads();
    float* o = sw + bx * 49;
    if (wv == 0 && lane < 25) {
        float s = red[0][lane] + red[1][lane] + b1[co];
        o[lane] = 1.f / (1.f + expf(-s));
    } else if (wv == 1 && lane < 24) {
        float s = red[2][lane] + red[3][lane] + b1[co];
        o[25 + lane] = 1.f / (1.f + expf(-s));
    }
}

// ---------------------------------------------------------------------------
// K3: tail.  sw -> LDS; convf (K=5,s=4,p=2) -> 1+r[169]; feat_f = attended
// mean of features_f; head Linear(1536->3). One block per batch element.
__global__ __launch_bounds__(256) void k_tail(const float* __restrict__ sw,
                                              const float* __restrict__ cw,
                                              const float* __restrict__ cb,
                                              const float* __restrict__ ff,
                                              const float* __restrict__ fo,
                                              const float* __restrict__ hw,
                                              const float* __restrict__ hb,
                                              float* __restrict__ out) {
    __shared__ float swl[3136];
    __shared__ float r1[169];
    __shared__ float feat[512];
    int b = blockIdx.x;
    int t = threadIdx.x;
    for (int idx = t; idx < 3136; idx += 256) swl[idx] = sw[b * 3136 + idx];
    __syncthreads();
    if (t < 169) {
        int o = t / 13, l = t % 13;
        float s = cb[o];
        for (int i = 0; i < 64; i++) {
#pragma unroll
            for (int k = 0; k < 5; k++) {
                int pos = 4 * l + k - 2;
                if (pos >= 0 && pos < 49)
                    s += swl[i * 49 + pos] * cw[(o * 64 + i) * 5 + k];
            }
        }
        r1[t] = 1.f + 1.f / (1.f + expf(-s));
    }
    __syncthreads();
    int wave = t >> 6, lane = t & 63;
    for (int c = wave; c < 512; c += 4) {
        const float* row = ff + (size_t)(b * 512 + c) * 169;
        float s = 0.f;
        for (int p = lane; p < 169; p += 64) s += row[p] * r1[p];
#pragma unroll
        for (int off = 32; off >= 1; off >>= 1) s += __shfl_xor(s, off);
        if (lane == 0) feat[c] = s * (1.0f / 169.0f);
    }
    __syncthreads();
    if (t < 192) {
        int j = t >> 6;
        float s = 0.f;
        for (int i = lane; i < 1536; i += 64) {
            float fv = (i < 512) ? feat[i] : fo[b * 1024 + (i - 512)];
            s += fv * hw[j * 1536 + i];
        }
#pragma unroll
        for (int off = 32; off >= 1; off >>= 1) s += __shfl_xor(s, off);
        if (lane == 0) out[b * 3 + j] = s + hb[j];
    }
}

// ---------------------------------------------------------------------------
extern "C" void kernel_launch(void* const* d_in, const int* in_sizes, int n_in,
                              void* d_out, int out_size, void* d_ws, size_t ws_size,
                              hipStream_t stream) {
    const float* ff  = (const float*)d_in[0];  // features_f [4,512,13,13]
    const float* oct = (const float*)d_in[1];  // oct_feats  [4,112,512,16,16]
    const float* w1  = (const float*)d_in[2];  // conv1d_w   [64,1024,64]
    const float* b1  = (const float*)d_in[3];  // conv1d_b   [64]
    const float* cw  = (const float*)d_in[4];  // convf_w    [13,64,5]
    const float* cb  = (const float*)d_in[5];  // convf_b    [13]
    const float* hw  = (const float*)d_in[6];  // head_w     [3,1536]
    const float* hb  = (const float*)d_in[7];  // head_b     [3]
    float* out = (float*)d_out;                // [4,3]
    char* ws = (char*)d_ws;
    __hip_bfloat16* xb = (__hip_bfloat16*)(ws + XB_OFF);
    float*          fo = (float*)(ws + FO_OFF);
    float*          sw = (float*)(ws + SW_OFF);

    hipLaunchKernelGGL(k_pool, dim3(2048), dim3(256), 0, stream, oct, xb, fo);
    hipLaunchKernelGGL(k_conv, dim3(256),  dim3(256), 0, stream, xb, w1, b1, sw);
    hipLaunchKernelGGL(k_tail, dim3(4),    dim3(256), 0, stream,
                       sw, cw, cb, ff, fo, hw, hb, out);
}

// Round 5
// 465.841 us; speedup vs baseline: 1.2921x; 1.2921x over previous
//
#include <hip/hip_runtime.h>
#include <hip/hip_bf16.h>
#include <math.h>

// Workspace layout (bytes) — max footprint 984,064 B (round-3 proven size).
//   xb  : [4][1024][112] bf16  @ 0        (917,504)  conv input (fv | fv_max)
//   fo  : [4][1024]      f32   @ 917504   ( 16,384)  feat_o
//   am  : [4][512]       u64   @ 933888   ( 16,384)  argmax keys (aliases sw slot)
//   sw  : [4][64][49]    f32   @ 933888   ( 50,176)  slice weights (after am is dead)
//   rf  : [4][169]       f32   @ 0        (  2,704)  1+r  (aliases dead xb)
//   feat: [4][512]       f32   @ 933888   (  8,192)  feat_f (aliases dead sw)
// Stream-order reuse: am dead after k_feato -> k_conv writes sw; xb dead after
// k_conv -> k_r writes rf; sw dead after k_r -> k_ff writes feat.
#define XB_OFF 0
#define FO_OFF 917504
#define AM_OFF 933888
#define SW_OFF 933888
#define RF_OFF 0
#define FT_OFF 933888

// ---------------------------------------------------------------------------
// K0: zero the 2048 argmax keys (ws is re-poisoned before every launch).
__global__ __launch_bounds__(256) void k_init(unsigned long long* __restrict__ am) {
    am[blockIdx.x * 256 + threadIdx.x] = 0ULL;
}

// ---------------------------------------------------------------------------
// K1: pool. One wave per (b,m,c): 64 lanes x float4 = the full 16x16 map.
// Butterfly reduce sum/max; lane 0 writes bf16 fv/fv_max AND a packed fp32
// argmax key: (order-flipped fv_max bits << 32) | (111-m).  atomicMax gives
// max-by-fp32-value with smallest-m tie-break (np.argmax first-occurrence).
__global__ __launch_bounds__(256) void k_pool(const float* __restrict__ oct,
                                              __hip_bfloat16* __restrict__ xb,
                                              unsigned long long* __restrict__ am) {
    int wg = (blockIdx.x * 256 + threadIdx.x) >> 6;   // (b*112+m)*512+c
    int lane = threadIdx.x & 63;
    const float4* p = (const float4*)(oct + (size_t)wg * 256);
    float4 v = p[lane];
    float s  = v.x + v.y + v.z + v.w;
    float mx = fmaxf(fmaxf(v.x, v.y), fmaxf(v.z, v.w));
#pragma unroll
    for (int off = 32; off >= 1; off >>= 1) {
        s  += __shfl_xor(s, off);
        mx  = fmaxf(mx, __shfl_xor(mx, off));
    }
    if (lane == 0) {
        int c  = wg & 511;
        int bm = wg >> 9;
        int m  = bm % 112;
        int b  = bm / 112;
        xb[((size_t)b * 1024 + c) * 112 + m]       = __float2bfloat16(s * (1.0f / 256.0f));
        xb[((size_t)b * 1024 + 512 + c) * 112 + m] = __float2bfloat16(mx);
        unsigned int u = __float_as_uint(mx);
        unsigned int key = (u & 0x80000000u) ? ~u : (u | 0x80000000u);
        unsigned long long pk = ((unsigned long long)key << 32) | (unsigned int)(111 - m);
        atomicMax(&am[b * 512 + c], pk);
    }
}

// ---------------------------------------------------------------------------
// K2: feat_o.  feat_o_avg[b,c] = max_m fv (bf16-rounded, no index selection);
//              feat_o_max[b,c] = fv[b, m*, c] with m* from the fp32 atomic key.
__global__ __launch_bounds__(256) void k_feato(const __hip_bfloat16* __restrict__ xb,
                                               const unsigned long long* __restrict__ am,
                                               float* __restrict__ fo) {
    int wid  = blockIdx.x * 4 + (threadIdx.x >> 6);   // b*512+c
    int lane = threadIdx.x & 63;
    int b = wid >> 9, c = wid & 511;
    const __hip_bfloat16* fvrow = xb + ((size_t)b * 1024 + c) * 112;
    float v0 = (lane < 112)      ? __bfloat162float(fvrow[lane])      : -INFINITY;
    float v1 = (lane + 64 < 112) ? __bfloat162float(fvrow[lane + 64]) : -INFINITY;
    float mxf = fmaxf(v0, v1);
#pragma unroll
    for (int off = 32; off >= 1; off >>= 1)
        mxf = fmaxf(mxf, __shfl_xor(mxf, off));
    if (lane == 0) {
        int mstar = 111 - (int)(unsigned int)(am[b * 512 + c] & 0xFFFFFFFFULL);
        fo[b * 1024 + c]       = mxf;
        fo[b * 1024 + 512 + c] = __bfloat162float(fvrow[mstar]);
    }
}

// ---------------------------------------------------------------------------
// K3: conv1d (Cin=1024, K=64, L=112 -> 49). Block = (b, co, l-half); 512 blocks
// -> 2 blocks/CU. Per chunk of 256 ci staged in LDS (rows padded to 61 uints:
// stride 61 mod 32 = 29, coprime -> 2-way free), each wave owns 64 ci; the
// 88-value x-window is unpacked to REGISTERS (44 b32 LDS reads, no u16 reads).
__global__ __launch_bounds__(256) void k_conv(const __hip_bfloat16* __restrict__ xb,
                                              const float* __restrict__ w1,
                                              const float* __restrict__ b1,
                                              float* __restrict__ sw) {
    __shared__ unsigned int xs[256 * 61];   // 62,464 B
    __shared__ float red[4][25];
    int bx = blockIdx.x;
    int lh = bx & 1, co = (bx >> 1) & 63, b = bx >> 7;
    int t = threadIdx.x, wv = t >> 6, lane = t & 63;
    int l0u = lh * 12;                      // uint offset of window start (bf16 l0=24*lh)
    float acc[25];
#pragma unroll
    for (int i = 0; i < 25; i++) acc[i] = 0.f;
    const unsigned int* gxb = (const unsigned int*)xb;
    for (int chunk = 0; chunk < 4; chunk++) {
        __syncthreads();
        for (int r = wv; r < 256; r += 4)
            if (lane < 56)
                xs[r * 61 + lane] = gxb[((size_t)b * 1024 + chunk * 256 + r) * 56 + lane];
        __syncthreads();
        int cil = wv * 64 + lane;
        int ci  = chunk * 256 + cil;
        const unsigned int* xu = xs + cil * 61 + l0u;
        float xf[88];
#pragma unroll
        for (int i = 0; i < 44; i++) {
            unsigned int u = xu[i];
            xf[2 * i]     = __uint_as_float(u << 16);
            xf[2 * i + 1] = __uint_as_float(u & 0xffff0000u);
        }
        const float* wrow = w1 + ((size_t)co * 1024 + ci) * 64;
#pragma unroll
        for (int kc = 0; kc < 4; kc++) {
            float ww[16];
#pragma unroll
            for (int j = 0; j < 16; j++) ww[j] = wrow[kc * 16 + j];
#pragma unroll
            for (int k = 0; k < 16; k++)
#pragma unroll
                for (int i = 0; i < 25; i++)
                    acc[i] += ww[k] * xf[kc * 16 + k + i];
        }
    }
#pragma unroll
    for (int i = 0; i < 25; i++) {
#pragma unroll
        for (int off = 32; off >= 1; off >>= 1)
            acc[i] += __shfl_xor(acc[i], off);
    }
    if (lane < 25) red[wv][lane] = acc[lane];
    __syncthreads();
    if (t < 25) {
        float s = red[0][t] + red[1][t] + red[2][t] + red[3][t] + b1[co];
        float sg = 1.f / (1.f + expf(-s));
        int l = lh * 24 + t;                // lh=0: 0..24; lh=1: 24..48 (24 dup-dropped)
        if (!(lh == 1 && t == 0))
            sw[(size_t)(b * 64 + co) * 49 + l] = sg;
    }
}

// ---------------------------------------------------------------------------
// K4: convf (K=5, stride=4, pad=2) -> rf = 1+sigmoid. All inputs in LDS.
__global__ __launch_bounds__(256) void k_r(const float* __restrict__ sw,
                                           const float* __restrict__ cw,
                                           const float* __restrict__ cb,
                                           float* __restrict__ rf) {
    __shared__ float swl[3136];
    __shared__ float cwl[4160];
    int b = blockIdx.x, t = threadIdx.x;
    for (int i = t; i < 3136; i += 256) swl[i] = sw[b * 3136 + i];
    for (int i = t; i < 4160; i += 256) cwl[i] = cw[i];
    __syncthreads();
    if (t < 169) {
        int o = t / 13, l = t % 13;
        float s = cb[o];
        for (int i = 0; i < 64; i++) {
#pragma unroll
            for (int k = 0; k < 5; k++) {
                int pos = 4 * l + k - 2;
                if (pos >= 0 && pos < 49)
                    s += swl[i * 49 + pos] * cwl[(o * 64 + i) * 5 + k];
            }
        }
        rf[b * 169 + t] = 1.f + 1.f / (1.f + expf(-s));
    }
}

// ---------------------------------------------------------------------------
// K5: feat_f[b,c] = (1/169) sum_p ff[b,c,p] * rf[b,p]. Block = (b, 64-chan
// group); each wave does 16 independent dots. 32 blocks.
__global__ __launch_bounds__(256) void k_ff(const float* __restrict__ ff,
                                            const float* __restrict__ rf,
                                            float* __restrict__ feat) {
    __shared__ float r1[169];
    int b = blockIdx.x >> 3, cg = blockIdx.x & 7;
    int t = threadIdx.x, wv = t >> 6, lane = t & 63;
    if (t < 169) r1[t] = rf[b * 169 + t];
    __syncthreads();
#pragma unroll
    for (int j = 0; j < 16; j++) {
        int c = cg * 64 + wv * 16 + j;
        const float* row = ff + ((size_t)b * 512 + c) * 169;
        float s = row[lane] * r1[lane];
        if (lane + 64 < 169)  s += row[lane + 64]  * r1[lane + 64];
        if (lane + 128 < 169) s += row[lane + 128] * r1[lane + 128];
#pragma unroll
        for (int off = 32; off >= 1; off >>= 1) s += __shfl_xor(s, off);
        if (lane == 0) feat[b * 512 + c] = s * (1.0f / 169.0f);
    }
}

// ---------------------------------------------------------------------------
// K6: head Linear(1536 -> 3). One block per (b, j).
__global__ __launch_bounds__(256) void k_head(const float* __restrict__ feat,
                                              const float* __restrict__ fo,
                                              const float* __restrict__ hw,
                                              const float* __restrict__ hb,
                                              float* __restrict__ out) {
    __shared__ float red[4];
    int bj = blockIdx.x;
    int b = bj / 3, j = bj % 3;
    int t = threadIdx.x, wv = t >> 6, lane = t & 63;
    float s = 0.f;
#pragma unroll
    for (int rep = 0; rep < 6; rep++) {
        int i = rep * 256 + t;
        float fv = (i < 512) ? feat[b * 512 + i] : fo[b * 1024 + (i - 512)];
        s += fv * hw[j * 1536 + i];
    }
#pragma unroll
    for (int off = 32; off >= 1; off >>= 1) s += __shfl_xor(s, off);
    if (lane == 0) red[wv] = s;
    __syncthreads();
    if (t == 0)
        out[b * 3 + j] = red[0] + red[1] + red[2] + red[3] + hb[j];
}

// ---------------------------------------------------------------------------
extern "C" void kernel_launch(void* const* d_in, const int* in_sizes, int n_in,
                              void* d_out, int out_size, void* d_ws, size_t ws_size,
                              hipStream_t stream) {
    const float* ff  = (const float*)d_in[0];  // features_f [4,512,13,13]
    const float* oct = (const float*)d_in[1];  // oct_feats  [4,112,512,16,16]
    const float* w1  = (const float*)d_in[2];  // conv1d_w   [64,1024,64]
    const float* b1  = (const float*)d_in[3];  // conv1d_b   [64]
    const float* cw  = (const float*)d_in[4];  // convf_w    [13,64,5]
    const float* cb  = (const float*)d_in[5];  // convf_b    [13]
    const float* hw  = (const float*)d_in[6];  // head_w     [3,1536]
    const float* hb  = (const float*)d_in[7];  // head_b     [3]
    float* out = (float*)d_out;                // [4,3]
    char* ws = (char*)d_ws;
    __hip_bfloat16*     xb = (__hip_bfloat16*)(ws + XB_OFF);
    float*              fo = (float*)(ws + FO_OFF);
    unsigned long long* am = (unsigned long long*)(ws + AM_OFF);
    float*              sw = (float*)(ws + SW_OFF);  // after am is dead
    float*              rf = (float*)(ws + RF_OFF);  // aliases dead xb
    float*            feat = (float*)(ws + FT_OFF);  // aliases dead sw

    hipLaunchKernelGGL(k_init,  dim3(8),     dim3(256), 0, stream, am);
    hipLaunchKernelGGL(k_pool,  dim3(57344), dim3(256), 0, stream, oct, xb, am);
    hipLaunchKernelGGL(k_feato, dim3(512),   dim3(256), 0, stream, xb, am, fo);
    hipLaunchKernelGGL(k_conv,  dim3(512),   dim3(256), 0, stream, xb, w1, b1, sw);
    hipLaunchKernelGGL(k_r,     dim3(4),     dim3(256), 0, stream, sw, cw, cb, rf);
    hipLaunchKernelGGL(k_ff,    dim3(32),    dim3(256), 0, stream, ff, rf, feat);
    hipLaunchKernelGGL(k_head,  dim3(12),    dim3(256), 0, stream, feat, fo, hw, hb, out);
}